// Round 1
// baseline (804.566 us; speedup 1.0000x reference)
//
#include <hip/hip_runtime.h>
#include <math.h>

// ---------------------------------------------------------------------------
// SplineCNN-style net on MI355X. Round 0: straightforward correct pipeline.
// Levels: pool_max -> spline_conv(+ELU)  x5, dense pool -> FC -> log_softmax.
// ---------------------------------------------------------------------------

// Monotone mapping: float -> unsigned preserving order, so atomicMax works.
__device__ __forceinline__ unsigned f2mono(float f) {
    unsigned u = __float_as_uint(f);
    return (u & 0x80000000u) ? ~u : (u | 0x80000000u);
}
__device__ __forceinline__ float mono2f(unsigned m) {
    unsigned u = (m & 0x80000000u) ? (m & 0x7FFFFFFFu) : ~m;
    return __uint_as_float(u);
}

__global__ void fill_u32(unsigned* __restrict__ p, int n, unsigned v) {
    int i = blockIdx.x * blockDim.x + threadIdx.x;
    if (i < n) p[i] = v;
}

// scatter max: x [n_in, C] -> mono [n_out, C] via cluster ids
__global__ void pool_scatter(const float* __restrict__ x, const int* __restrict__ cl,
                             unsigned* __restrict__ mono, int n_in, int C) {
    int i = blockIdx.x * blockDim.x + threadIdx.x;
    if (i >= n_in * C) return;
    int node = i / C;
    int c = i - node * C;
    atomicMax(&mono[cl[node] * C + c], f2mono(x[i]));
}

__global__ void pool_final(const unsigned* __restrict__ mono, float* __restrict__ out, int n) {
    int i = blockIdx.x * blockDim.x + threadIdx.x;
    if (i < n) {
        unsigned m = mono[i];
        out[i] = (m == 0u) ? 0.f : mono2f(m);  // sentinel 0 == empty segment
    }
}

// One block per edge, COUT threads. x[src] staged in LDS; 8 B-spline corners.
template <int CIN, int COUT>
__global__ void spline_edge(const float* __restrict__ x, const int* __restrict__ src,
                            const int* __restrict__ dst, const float* __restrict__ pseudo,
                            const float* __restrict__ W, float* __restrict__ agg,
                            float* __restrict__ deg, int E) {
    int e = blockIdx.x;
    if (e >= E) return;
    int t = threadIdx.x;  // 0..COUT-1
    __shared__ float xs[CIN];
    __shared__ float fr[3];
    __shared__ int ff[3];
    int s = src[e];
    int dd = dst[e];
    if (t < CIN) xs[t] = x[(size_t)s * CIN + t];
    if (t < 3) {
        float p = pseudo[(size_t)e * 3 + t] * 4.0f;  // (K-1) = 4
        float f = floorf(p);
        ff[t] = (int)f;
        fr[t] = p - f;
    }
    if (t == 0) atomicAdd(&deg[dd], 1.0f);
    __syncthreads();
    float acc = 0.f;
#pragma unroll
    for (int bits = 0; bits < 8; ++bits) {
        float w = 1.f;
        int idx = 0;
        int pw = 1;
#pragma unroll
        for (int d = 0; d < 3; ++d) {
            int b = (bits >> d) & 1;
            w *= b ? fr[d] : (1.f - fr[d]);
            int fd = ff[d] + b;
            fd = fd < 0 ? 0 : (fd > 4 ? 4 : fd);
            idx += fd * pw;
            pw *= 5;
        }
        const float* Wk = W + ((size_t)idx * CIN) * COUT + t;
        float a2 = 0.f;
#pragma unroll
        for (int i = 0; i < CIN; ++i) a2 += xs[i] * Wk[(size_t)i * COUT];
        acc += w * a2;
    }
    atomicAdd(&agg[(size_t)dd * COUT + t], acc);
}

// y = elu(agg/max(deg,1) + x@root + bias)
template <int CIN, int COUT>
__global__ void conv_finish(const float* __restrict__ x, const float* __restrict__ agg,
                            const float* __restrict__ deg, const float* __restrict__ root,
                            const float* __restrict__ bias, float* __restrict__ y, int N) {
    int tid = blockIdx.x * blockDim.x + threadIdx.x;
    if (tid >= N * COUT) return;
    int n = tid / COUT;
    int c = tid - n * COUT;
    float d = deg[n];
    d = d > 1.f ? d : 1.f;
    float v = agg[tid] / d;
#pragma unroll
    for (int i = 0; i < CIN; ++i) v += x[(size_t)n * CIN + i] * root[(size_t)i * COUT + c];
    v += bias[c];
    y[tid] = v > 0.f ? v : expm1f(v);
}

// fc1: [1024] @ [1024,512] + b, ELU
__global__ void fc1_kernel(const float* __restrict__ x, const float* __restrict__ w,
                           const float* __restrict__ b, float* __restrict__ out) {
    int o = blockIdx.x * blockDim.x + threadIdx.x;
    if (o >= 512) return;
    float acc = b[o];
#pragma unroll 8
    for (int i = 0; i < 1024; ++i) acc += x[i] * w[(size_t)i * 512 + o];
    out[o] = acc > 0.f ? acc : expm1f(acc);
}

// fc2 (512->10) + log_softmax, single small block
__global__ void fc2_lsm(const float* __restrict__ x, const float* __restrict__ w,
                        const float* __restrict__ b, float* __restrict__ out) {
    __shared__ float z[10];
    int t = threadIdx.x;
    if (t < 10) {
        float acc = b[t];
        for (int i = 0; i < 512; ++i) acc += x[i] * w[(size_t)i * 10 + t];
        z[t] = acc;
    }
    __syncthreads();
    if (t == 0) {
        float m = z[0];
        for (int i = 1; i < 10; ++i) m = fmaxf(m, z[i]);
        float s = 0.f;
        for (int i = 0; i < 10; ++i) s += expf(z[i] - m);
        float l = logf(s);
        for (int i = 0; i < 10; ++i) out[i] = z[i] - m - l;
    }
}

// ---------------------------------------------------------------------------

template <int CIN, int COUT>
static void run_conv(const float* x, const int* src, const int* dst, const float* ps,
                     const float* W, const float* root, const float* bias, float* y,
                     float* tmp, int N, int E, hipStream_t stream) {
    float* agg = tmp;
    float* deg = tmp + (size_t)N * COUT;
    int nz = N * COUT + N;
    fill_u32<<<(nz + 255) / 256, 256, 0, stream>>>((unsigned*)agg, nz, 0u);  // 0u == 0.0f
    spline_edge<CIN, COUT><<<E, COUT, 0, stream>>>(x, src, dst, ps, W, agg, deg, E);
    int nf = N * COUT;
    conv_finish<CIN, COUT><<<(nf + 255) / 256, 256, 0, stream>>>(x, agg, deg, root, bias, y, N);
}

extern "C" void kernel_launch(void* const* d_in, const int* in_sizes, int n_in,
                              void* d_out, int out_size, void* d_ws, size_t ws_size,
                              hipStream_t stream) {
    // setup_inputs() dict order:
    // 0: x0; 1..6: cluster1..6; then per level i(0..4) at base 7+6i:
    //   src, dst, pseudo, W, root, b; 37: fc1_w, 38: fc1_b, 39: fc2_w, 40: fc2_b
    const float* x0 = (const float*)d_in[0];
    const int* cl[6];
    for (int i = 0; i < 6; ++i) cl[i] = (const int*)d_in[1 + i];
    const int* src[5];
    const int* dst[5];
    const float* ps[5];
    const float* W[5];
    const float* root[5];
    const float* bias[5];
    for (int i = 0; i < 5; ++i) {
        src[i] = (const int*)d_in[7 + 6 * i];
        dst[i] = (const int*)d_in[8 + 6 * i];
        ps[i] = (const float*)d_in[9 + 6 * i];
        W[i] = (const float*)d_in[10 + 6 * i];
        root[i] = (const float*)d_in[11 + 6 * i];
        bias[i] = (const float*)d_in[12 + 6 * i];
    }
    const float* fc1_w = (const float*)d_in[37];
    const float* fc1_b = (const float*)d_in[38];
    const float* fc2_w = (const float*)d_in[39];
    const float* fc2_b = (const float*)d_in[40];

    float* ws = (float*)d_ws;
    float* xp1 = ws;              // 20000   (pool of x0)
    float* y1 = xp1 + 20000;      // 640000  (20000 x 32)
    float* xp2 = y1 + 640000;     // 192000  (6000 x 32)
    float* y2 = xp2 + 192000;     // 384000  (6000 x 64)
    float* xp3 = y2 + 384000;     // 128000  (2000 x 64)
    float* y3 = xp3 + 128000;     // 128000  (2000 x 64)
    float* xp4 = y3 + 128000;     // 44800   (700 x 64)
    float* y4 = xp4 + 44800;      // 44800   (700 x 64)
    float* xp5 = y4 + 44800;      // 16384   (256 x 64)
    float* y5 = xp5 + 16384;      // 32768   (256 x 128)
    float* xp6 = y5 + 32768;      // 1024    (8 x 128)
    float* fc1o = xp6 + 1024;     // 512
    float* tmp = fc1o + 512;      // 660000 max (agg+deg / mono), reused per stage

    auto pool = [&](const float* xin, const int* c, float* xout, int n_in2, int n_out, int C) {
        unsigned* mono = (unsigned*)tmp;
        int nmono = n_out * C;
        fill_u32<<<(nmono + 255) / 256, 256, 0, stream>>>(mono, nmono, 0u);
        int ns = n_in2 * C;
        pool_scatter<<<(ns + 255) / 256, 256, 0, stream>>>(xin, c, mono, n_in2, C);
        pool_final<<<(nmono + 255) / 256, 256, 0, stream>>>(mono, xout, nmono);
    };

    // level 1
    pool(x0, cl[0], xp1, 80000, 20000, 1);
    run_conv<1, 32>(xp1, src[0], dst[0], ps[0], W[0], root[0], bias[0], y1, tmp, 20000, 160000, stream);
    // level 2
    pool(y1, cl[1], xp2, 20000, 6000, 32);
    run_conv<32, 64>(xp2, src[1], dst[1], ps[1], W[1], root[1], bias[1], y2, tmp, 6000, 48000, stream);
    // level 3
    pool(y2, cl[2], xp3, 6000, 2000, 64);
    run_conv<64, 64>(xp3, src[2], dst[2], ps[2], W[2], root[2], bias[2], y3, tmp, 2000, 16000, stream);
    // level 4
    pool(y3, cl[3], xp4, 2000, 700, 64);
    run_conv<64, 64>(xp4, src[3], dst[3], ps[3], W[3], root[3], bias[3], y4, tmp, 700, 5600, stream);
    // level 5
    pool(y4, cl[4], xp5, 700, 256, 64);
    run_conv<64, 128>(xp5, src[4], dst[4], ps[4], W[4], root[4], bias[4], y5, tmp, 256, 2048, stream);
    // final dense pool to 8 nodes -> [1,1024]
    pool(y5, cl[5], xp6, 256, 8, 128);
    // FC head
    fc1_kernel<<<2, 256, 0, stream>>>(xp6, fc1_w, fc1_b, fc1o);
    fc2_lsm<<<1, 64, 0, stream>>>(fc1o, fc2_w, fc2_b, (float*)d_out);
}